// Round 4
// baseline (38.718 us; speedup 1.0000x reference)
//
#include <hip/hip_runtime.h>

// Problem constants (from reference setup_inputs)
#define BB 32
#define CC 64
#define HH 224
#define WW 224
#define HO 112
#define WO 112
#define OPH 17   // ceil((32 + 2 - 1) / 2)
#define OPW 17

#define IMG_F4   (CC * HO * WO / 4)   // 200704 float4 per image (= 256 * 784)
#define CH_F4    (HO * WO / 4)        // 3136 float4 per channel
#define ROW_F4   (WO / 4)             // 28 float4 per output row
#define TOTAL_F4 (BB * IMG_F4)        // 6422528 float4 total
#define BLK_PER_IMG (IMG_F4 / 256)    // 784 blocks per image (exact)

typedef float f32x4 __attribute__((ext_vector_type(4)));  // native vec: nt-builtin compatible

// Single fused pass: stream-copy stale pooled output (non-temporal, bypass L2),
// recomputing elements inside the per-image dirty 17x17 output window from the
// input tensor. Tail of d_out gets new_loc as float32.
__global__ __launch_bounds__(256)
void IncMaxPool_fused_kernel(const float* __restrict__ in,
                             const f32x4* __restrict__ prev,
                             const int* __restrict__ loc,
                             f32x4* __restrict__ out) {
    // b is uniform per block -> scalar loc load + scalar oy/ox math
    const int b   = blockIdx.x / BLK_PER_IMG;
    const int tid = blockIdx.x * 256 + threadIdx.x;
    const int r0  = tid - b * IMG_F4;          // float4 index within image

    const int l0 = loc[b * 2 + 0];
    const int l1 = loc[b * 2 + 1];
    const int oy = min(max(l0 >> 1, 0), HO - OPH);
    const int ox = min(max(l1 >> 1, 0), WO - OPW);

    // decompose within-image index -> (c, y, x4)
    const int c  = r0 / CH_F4;
    const int r1 = r0 - c * CH_F4;
    const int y  = r1 / ROW_F4;
    const int x4 = (r1 - y * ROW_F4) * 4;

    f32x4 v = __builtin_nontemporal_load(&prev[tid]);

    if (y >= oy && y < oy + OPH && (x4 + 3) >= ox && x4 <= (ox + OPW - 1)) {
        const float* ib = in + (size_t)(b * CC + c) * (HH * WW) + (size_t)(y * 2) * WW;
        #pragma unroll
        for (int j = 0; j < 4; ++j) {
            const int x = x4 + j;
            if (x >= ox && x < ox + OPW) {
                const float2 a = *(const float2*)(ib + x * 2);        // row y*2
                const float2 d = *(const float2*)(ib + WW + x * 2);   // row y*2+1
                v[j] = fmaxf(fmaxf(a.x, a.y), fmaxf(d.x, d.y));
            }
        }
    }

    __builtin_nontemporal_store(v, &out[tid]);

    // new_loc tail: 32 (oy, ox) pairs as floats
    if (tid < BB) {
        const int m0 = loc[tid * 2 + 0];
        const int m1 = loc[tid * 2 + 1];
        float* locout = (float*)out + (size_t)BB * CC * HO * WO;
        locout[tid * 2 + 0] = (float)min(max(m0 >> 1, 0), HO - OPH);
        locout[tid * 2 + 1] = (float)min(max(m1 >> 1, 0), WO - OPW);
    }
}

extern "C" void kernel_launch(void* const* d_in, const int* in_sizes, int n_in,
                              void* d_out, int out_size, void* d_ws, size_t ws_size,
                              hipStream_t stream) {
    const float* in_tensor  = (const float*)d_in[0];
    const f32x4* out_tensor = (const f32x4*)d_in[1];
    const int*   loc        = (const int*)d_in[2];
    f32x4* out = (f32x4*)d_out;

    IncMaxPool_fused_kernel<<<TOTAL_F4 / 256, 256, 0, stream>>>(in_tensor, out_tensor, loc, out);
}